// Round 19
// baseline (712.069 us; speedup 1.0000x reference)
//
#include <hip/hip_runtime.h>
#include <hip/hip_bf16.h>
#include <cstdint>

#define NB 32
#define NT 2000
#define TP 2048
#define NENC 1024
#define NDEC 1024
#define NATTN 512
#define NHEAD 4
#define NH 2048      // NHEAD*NATTN
#define NC 64
#define NKS 50
#define NKLEN 101
#define NPH 256
#define NPROF 101
#define NTS 16       // k_ctx t-splits
#define TCH 125      // t per split

typedef __attribute__((ext_vector_type(8))) short bf16x8;
typedef __attribute__((ext_vector_type(4))) float f32x4;
typedef __attribute__((ext_vector_type(8))) unsigned short u16x8;

__device__ __forceinline__ void gload_lds16(const void* g, void* l) {
    __builtin_amdgcn_global_load_lds((__attribute__((address_space(1))) void*)(g),
                                     (__attribute__((address_space(3))) void*)(l), 16, 0, 0);
}

__device__ __forceinline__ unsigned short f2bf(float f) {
    unsigned u = __float_as_uint(f);
    return (unsigned short)((u + 0x7fffu + ((u >> 16) & 1u)) >> 16);
}

__device__ __forceinline__ float bf2f(unsigned short u) {
    return __uint_as_float((unsigned)u << 16);
}

__device__ __forceinline__ int prof_of(int t, int len) {
    if (t < NKS) return t;
    if (t < len - NKS) return NKS;
    if (t < len) return NKS + 1 + (t - (len - NKS));
    return NKS;
}

__device__ __forceinline__ float4 f4add3(float4 a, float4 b, float4 c) {
    return make_float4(a.x + b.x + c.x, a.y + b.y + c.y, a.z + b.z + c.z, a.w + b.w + c.w);
}
__device__ __forceinline__ float4 f4fma(float s, float4 a, float4 acc) {
    return make_float4(fmaf(s, a.x, acc.x), fmaf(s, a.y, acc.y),
                       fmaf(s, a.z, acc.z), fmaf(s, a.w, acc.w));
}
__device__ __forceinline__ float f4dot(float4 a, float4 b) {
    return fmaf(a.x, b.x, fmaf(a.y, b.y, fmaf(a.z, b.z, a.w * b.w)));
}

// ------------- fused f32 -> bf16 conversion for enc AND Wenc (one launch) -----
__global__ void k_convert2(const float* __restrict__ srcA, unsigned short* __restrict__ dstA, int n8A,
                           const float* __restrict__ srcB, unsigned short* __restrict__ dstB, int n8B) {
    int stride = gridDim.x * blockDim.x;
    int total = n8A + n8B;
    for (int i = blockIdx.x * blockDim.x + threadIdx.x; i < total; i += stride) {
        const float* src; unsigned short* dst; int j;
        if (i < n8A) { src = srcA; dst = dstA; j = i; }
        else         { src = srcB; dst = dstB; j = i - n8A; }
        const float4* s = (const float4*)(src) + (size_t)j * 2;
        float4 x = s[0], y = s[1];
        u16x8 o;
        o[0] = f2bf(x.x); o[1] = f2bf(x.y); o[2] = f2bf(x.z); o[3] = f2bf(x.w);
        o[4] = f2bf(y.x); o[5] = f2bf(y.y); o[6] = f2bf(y.z); o[7] = f2bf(y.w);
        *((u16x8*)dst + j) = o;
    }
}

// ------- fused prep: wcum (block 0) | wlocT (blocks 1..64) | dech (65..192) ---
__global__ void k_prep(const float* __restrict__ Wconv, float* __restrict__ wcum,
                       const float* __restrict__ Wloc, float* __restrict__ wlocT,
                       const float* __restrict__ dec, const float* __restrict__ Wdec,
                       const float* __restrict__ bdec, float* __restrict__ dech) {
    int blk = blockIdx.x;
    int tid = threadIdx.x;
    if (blk == 0) {
        float c = 0.f;
        wcum[tid * 102] = 0.f;
        for (int k = 0; k < NKLEN; ++k) {
            c += Wconv[tid * NKLEN + k];
            wcum[tid * 102 + k + 1] = c;
        }
    } else if (blk <= 64) {
        int c = blk - 1;
        for (int n = tid; n < NH; n += 256)
            wlocT[c * NH + n] = Wloc[(size_t)n * NC + c];
    } else {
        int idx = blk - 65;
        int h = idx >> 5, b = idx & 31;
        __shared__ float dl[NDEC];
        for (int r = 0; r < 4; ++r) dl[tid + r * 256] = dec[b * NDEC + tid + r * 256];
        __syncthreads();
        for (int a2 = 0; a2 < 2; ++a2) {
            int a = tid + a2 * 256;
            const float4* wr = (const float4*)&Wdec[((size_t)(h * NATTN + a)) * NDEC];
            float acc = 0.f;
            for (int e4 = 0; e4 < NDEC / 4; ++e4) {
                float4 w4 = wr[e4];
                acc += w4.x * dl[e4 * 4] + w4.y * dl[e4 * 4 + 1] + w4.z * dl[e4 * 4 + 2] + w4.w * dl[e4 * 4 + 3];
            }
            dech[(h * NB + b) * NATTN + a] = acc + bdec[h * NATTN + a];
        }
    }
}

// ---- add[b][p][n] = dec_h + benc + bloc + WlocT^T . conv_profile(p), PP=8 ----
__global__ void k_addprof(const float* __restrict__ wcum, const float* __restrict__ dech,
                          const float* __restrict__ benc, const float* __restrict__ bloc,
                          const float* __restrict__ wlocT, const int* __restrict__ enc_len,
                          float* __restrict__ addp) {
    int p0 = blockIdx.x * 8, b = blockIdx.y;
    int len = enc_len[b];
    __shared__ float convp[8][256];
    int tid = threadIdx.x;
    float invl = 1.f / (float)len;
#pragma unroll
    for (int pp = 0; pp < 8; ++pp) {
        int p = min(p0 + pp, NPROF - 1);
        int kmin, kmax;
        if (p < NKS)       { kmin = NKS - p; kmax = min(NKLEN, len - p + NKS); }
        else if (p == NKS) { kmin = 0;       kmax = NKLEN; }
        else               { kmin = 0;       kmax = 151 - p; }
        if (kmax < kmin) kmax = kmin;
        convp[pp][tid] = (wcum[tid * 102 + kmax] - wcum[tid * 102 + kmin]) * invl;
    }
    __syncthreads();
    int h0 = tid >> 7, h1 = 2 + h0;
    int n40 = tid, n41 = 256 + tid;   // float4 indices into the 2048-wide n dim
    const float4* dech4 = (const float4*)dech;
    const float4* benc4 = (const float4*)benc;
    const float4* bloc4 = (const float4*)bloc;
    float4 base0 = f4add3(dech4[(h0 * NB + b) * 128 + (tid & 127)], benc4[n40], bloc4[n40]);
    float4 base1 = f4add3(dech4[(h1 * NB + b) * 128 + (tid & 127)], benc4[n41], bloc4[n41]);
    float4 acc[8][2];
#pragma unroll
    for (int pp = 0; pp < 8; ++pp) { acc[pp][0] = base0; acc[pp][1] = base1; }
    const float4* wT4 = (const float4*)wlocT;
#pragma unroll 2
    for (int c = 0; c < NC; ++c) {
        float4 w0 = wT4[c * 512 + n40];
        float4 w1 = wT4[c * 512 + n41];
#pragma unroll
        for (int pp = 0; pp < 8; ++pp) {
            acc[pp][0] = f4fma(convp[pp][h0 * 64 + c], w0, acc[pp][0]);
            acc[pp][1] = f4fma(convp[pp][h1 * 64 + c], w1, acc[pp][1]);
        }
    }
    float4* addp4 = (float4*)addp;
#pragma unroll
    for (int pp = 0; pp < 8; ++pp) {
        int p = p0 + pp;
        if (p < NPROF) {
            addp4[((size_t)(b * NPROF + p)) * 512 + n40] = acc[pp][0];
            addp4[((size_t)(b * NPROF + p)) * 512 + n41] = acc[pp][1];
        }
    }
}

// ---------------- main fused GEMM + tanh + wattn-reduce -> scores -------------
// v8: v5 with B moved OUT of LDS into registers. Cycle accounting showed v5 is
// LDS-pipe-bound (~2300 cyc/kt-gen of LDS reads+writes == wall). B's slice is
// L2-resident (4MB total) and its MFMA frag layout loads directly from
// row-major global (row n0+wc*64+n*16+ro, col kt*32+g4*8 -- no swizzle).
// LDS traffic per block-kt: 48KB -> 24KB. B double-buffered in regs (static
// even/odd bodies), prefetched 1 kt ahead; __syncthreads' vmcnt(0) sits a
// full compute phase after issue. ~96 VGPR + 64 AGPR = 160 <= 170 -> still
// 12 waves/CU (3 blocks).
__global__ __launch_bounds__(256, 3) void k_gemm(
        const unsigned short* __restrict__ encbf, const unsigned short* __restrict__ wencbf,
        const float* __restrict__ addp, const float* __restrict__ wattn,
        const int* __restrict__ enc_len, float* __restrict__ scores) {
    extern __shared__ char smem[];
    int bid = blockIdx.x;
    int L = (bid & 7) * 1024 + (bid >> 3);   // bijective XCD swizzle (8192%8==0)
    int nt = L & 15, ty = (L >> 4) & 15, b = L >> 8;
    int n0 = nt * 128, t0 = ty * 128;
    int len = enc_len[b];
    if (t0 >= len) return;  // fully-masked tile
    int tid = threadIdx.x, lane = tid & 63, w = tid >> 6;  // w in 0..3
    int wr = w >> 1, wc = w & 1;
    int ro = lane & 15, g4 = lane >> 4;

    int lrow = lane >> 2;
    int csrc = ((lane & 3) ^ ((lane >> 3) & 3)) * 8;   // elements (A staging swizzle)
    const unsigned short* aB = encbf + (size_t)b * NT * NENC;
    int rA[2];
#pragma unroll
    for (int g = 0; g < 2; ++g) { int t = t0 + g * 64 + w * 16 + lrow; rA[g] = t < NT ? t : NT - 1; }

    auto STAGE_A = [&](int q, int kt) {
        char* base = smem + q * 8192;
        int k0 = kt * 32 + csrc;
#pragma unroll
        for (int g = 0; g < 2; ++g)
            gload_lds16(aB + (size_t)rA[g] * NENC + k0, base + g * 4096 + w * 1024);
    };

    // B direct global->reg: lane (ro,g4) reads row n0+wc*64+n*16+ro, col kt*32+g4*8
    const unsigned short* bBase = wencbf + (size_t)(n0 + wc * 64 + ro) * NENC + g4 * 8;
    bf16x8 B0[4], B1[4];
#define LOADB(BF, KT) { _Pragma("unroll") \
    for (int n = 0; n < 4; ++n) BF[n] = *(const bf16x8*)(bBase + (size_t)n * 16 * NENC + (KT) * 32); }

    f32x4 acc[4][4] = {};
    int swb = (g4 ^ ((ro >> 1) & 3)) * 16;               // swizzled chunk byte on read
    int rdA = (wr * 64 + ro) * 64 + swb;                  // + m*1024

#define COMPUTE(BASE, BF) { \
    const char* base_ = (BASE); \
    bf16x8 A[4]; \
    _Pragma("unroll") \
    for (int m = 0; m < 4; ++m) A[m] = *(const bf16x8*)(base_ + rdA + m * 1024); \
    __builtin_amdgcn_s_setprio(1); \
    _Pragma("unroll") \
    for (int m = 0; m < 4; ++m) { \
        acc[m][0] = __builtin_amdgcn_mfma_f32_16x16x32_bf16(A[m], BF[0], acc[m][0], 0, 0, 0); \
        acc[m][1] = __builtin_amdgcn_mfma_f32_16x16x32_bf16(A[m], BF[1], acc[m][1], 0, 0, 0); \
        acc[m][2] = __builtin_amdgcn_mfma_f32_16x16x32_bf16(A[m], BF[2], acc[m][2], 0, 0, 0); \
        acc[m][3] = __builtin_amdgcn_mfma_f32_16x16x32_bf16(A[m], BF[3], acc[m][3], 0, 0, 0); } \
    __builtin_amdgcn_s_setprio(0); }

    STAGE_A(0, 0);
    LOADB(B0, 0);
    __syncthreads();
#pragma unroll 1
    for (int kp = 0; kp < 16; ++kp) {
        int kt1 = 2 * kp + 1;
        // even body: consume A-buf0 + B0; prefetch kt1 -> buf1/B1
        STAGE_A(1, kt1);
        LOADB(B1, kt1);
        COMPUTE(smem, B0);
        __syncthreads();
        // odd body: consume A-buf1 + B1; prefetch kt1+1 -> buf0/B0
        if (kp < 15) { STAGE_A(0, kt1 + 1); LOADB(B0, kt1 + 1); }
        COMPUTE(smem + 8192, B1);
        __syncthreads();
    }
#undef COMPUTE
#undef LOADB

    // epilogue: tanh(acc+add)*wattn, 16-lane reduce over n, atomicAdd to scores
    int h = n0 >> 9;
    float wat[4];
#pragma unroll
    for (int n = 0; n < 4; ++n) wat[n] = wattn[n0 + wc * 64 + n * 16 + ro];
    const float* addb = addp + (size_t)b * NPROF * NH + n0 + wc * 64 + ro;
    float* sr = scores + ((size_t)(h * NB + b)) * TP;
#pragma unroll
    for (int m = 0; m < 4; ++m) {
#pragma unroll
        for (int e = 0; e < 4; ++e) {
            int t = t0 + wr * 64 + m * 16 + g4 * 4 + e;
            int tc = t < NT ? t : NT - 1;
            const float* arow = addb + (size_t)prof_of(tc, len) * NH;
            float s = 0.f;
#pragma unroll
            for (int n = 0; n < 4; ++n) {
                float v = acc[m][n][e] + arow[n * 16];
                v = fminf(fmaxf(v, -15.f), 15.f);
                float e2 = __expf(2.f * v);
                s += ((e2 - 1.f) / (e2 + 1.f)) * wat[n];
            }
            s += __shfl_xor(s, 1); s += __shfl_xor(s, 2);
            s += __shfl_xor(s, 4); s += __shfl_xor(s, 8);
            if (ro == 0 && t < NT) atomicAdd(&sr[t], s);
        }
    }
}

// ------- masked softmax over t per (h,b) -> attn, + fused mean into out -------
__global__ void k_softmax(const float* __restrict__ scores, const int* __restrict__ enc_len,
                          float* __restrict__ attn, float* __restrict__ out) {
    int h = blockIdx.x >> 5, b = blockIdx.x & 31;
    int len = enc_len[b];
    int tid = threadIdx.x;
    const float* row = scores + ((size_t)(h * NB + b)) * TP;
    __shared__ float red[4];
    float m = -1e30f;
    for (int t = tid; t < len; t += 256) m = fmaxf(m, row[t]);
    for (int d = 32; d; d >>= 1) m = fmaxf(m, __shfl_xor(m, d));
    if ((tid & 63) == 0) red[tid >> 6] = m;
    __syncthreads();
    m = fmaxf(fmaxf(red[0], red[1]), fmaxf(red[2], red[3]));
    __syncthreads();
    float z = 0.f;
    for (int t = tid; t < len; t += 256) z += __expf(row[t] - m);
    for (int d = 32; d; d >>= 1) z += __shfl_xor(z, d);
    if ((tid & 63) == 0) red[tid >> 6] = z;
    __syncthreads();
    z = red[0] + red[1] + red[2] + red[3];
    float inv = 1.f / z;
    float* ow = out + NB * 1024 + b * NT;
    for (int t = tid; t < NT; t += 256) {
        float av = (t < len) ? __expf(row[t] - m) * inv : 0.f;
        attn[((size_t)(h * NB + b)) * NT + t] = av;
        atomicAdd(&ow[t], 0.25f * av);   // fused attn_weight mean over heads
    }
}

// ---- ctx partials: [ts][h][b][e], NTS=16 t-splits (4 blk/CU), unroll-2 -------
__global__ void k_ctx(const unsigned short* __restrict__ encbf, const float* __restrict__ attn,
                      const int* __restrict__ enc_len, float* __restrict__ ctxp) {
    int ec = blockIdx.x, ts = blockIdx.y, b = blockIdx.z;
    int tid = threadIdx.x;
    __shared__ float attnL[NHEAD][TCH];
    int t0 = ts * TCH;
    for (int i = tid; i < NHEAD * TCH; i += 256) {
        int hh = i / TCH, tt = i - hh * TCH;
        attnL[hh][tt] = attn[((size_t)(hh * NB + b)) * NT + t0 + tt];
    }
    __syncthreads();
    int len = enc_len[b];
    int t1 = min(t0 + TCH, len);
    int e0 = ec * 512 + tid * 2;
    const unsigned* erow = (const unsigned*)(encbf + (size_t)b * NT * NENC);
    float a0x = 0.f, a0y = 0.f, a1x = 0.f, a1y = 0.f;
    float a2x = 0.f, a2y = 0.f, a3x = 0.f, a3y = 0.f;
    int t = t0;
    for (; t + 2 <= t1; t += 2) {
        unsigned pv0 = erow[((size_t)t * NENC + e0) >> 1];
        unsigned pv1 = erow[((size_t)(t + 1) * NENC + e0) >> 1];
        int tt = t - t0;
        float ex0 = bf2f((unsigned short)(pv0 & 0xffff));
        float ey0 = bf2f((unsigned short)(pv0 >> 16));
        float w00 = attnL[0][tt], w10 = attnL[1][tt], w20 = attnL[2][tt], w30 = attnL[3][tt];
        a0x = fmaf(w00, ex0, a0x); a0y = fmaf(w00, ey0, a0y);
        a1x = fmaf(w10, ex0, a1x); a1y = fmaf(w10, ey0, a1y);
        a2x = fmaf(w20, ex0, a2x); a2y = fmaf(w20, ey0, a2y);
        a3x = fmaf(w30, ex0, a3x); a3y = fmaf(w30, ey0, a3y);
        float ex1 = bf2f((unsigned short)(pv1 & 0xffff));
        float ey1 = bf2f((unsigned short)(pv1 >> 16));
        float w01 = attnL[0][tt + 1], w11 = attnL[1][tt + 1], w21 = attnL[2][tt + 1], w31 = attnL[3][tt + 1];
        a0x = fmaf(w01, ex1, a0x); a0y = fmaf(w01, ey1, a0y);
        a1x = fmaf(w11, ex1, a1x); a1y = fmaf(w11, ey1, a1y);
        a2x = fmaf(w21, ex1, a2x); a2y = fmaf(w21, ey1, a2y);
        a3x = fmaf(w31, ex1, a3x); a3y = fmaf(w31, ey1, a3y);
    }
    for (; t < t1; ++t) {
        unsigned pv = erow[((size_t)t * NENC + e0) >> 1];
        float ex = bf2f((unsigned short)(pv & 0xffff));
        float ey = bf2f((unsigned short)(pv >> 16));
        int tt = t - t0;
        float w0 = attnL[0][tt], w1 = attnL[1][tt], w2 = attnL[2][tt], w3 = attnL[3][tt];
        a0x = fmaf(w0, ex, a0x); a0y = fmaf(w0, ey, a0y);
        a1x = fmaf(w1, ex, a1x); a1y = fmaf(w1, ey, a1y);
        a2x = fmaf(w2, ex, a2x); a2y = fmaf(w2, ey, a2y);
        a3x = fmaf(w3, ex, a3x); a3y = fmaf(w3, ey, a3y);
    }
    float2* c0 = (float2*)&ctxp[(((size_t)ts * NHEAD + 0) * NB + b) * NENC + e0];
    float2* c1 = (float2*)&ctxp[(((size_t)ts * NHEAD + 1) * NB + b) * NENC + e0];
    float2* c2 = (float2*)&ctxp[(((size_t)ts * NHEAD + 2) * NB + b) * NENC + e0];
    float2* c3 = (float2*)&ctxp[(((size_t)ts * NHEAD + 3) * NB + b) * NENC + e0];
    *c0 = make_float2(a0x, a0y);
    *c1 = make_float2(a1x, a1y);
    *c2 = make_float2(a2x, a2y);
    *c3 = make_float2(a3x, a3y);
}

// ------ out[h][b][o] = Wout[h,o,:].ctx + bout  (4-way ILP e-chains) -----------
__global__ void k_out(const float* __restrict__ ctxp, const float* __restrict__ Wout,
                      const float* __restrict__ bout, float* __restrict__ out) {
    int b = blockIdx.x, h = blockIdx.y;
    int tid = threadIdx.x;
    __shared__ __align__(16) float ctxL[NENC];
    for (int r = 0; r < 4; ++r) {
        int e = tid + r * 256;
        float s = 0.f;
#pragma unroll
        for (int s4 = 0; s4 < NTS; ++s4) s += ctxp[(((size_t)s4 * NHEAD + h) * NB + b) * NENC + e];
        ctxL[e] = s;
    }
    __syncthreads();
    int o = tid;
    const float4* wrow = (const float4*)&Wout[((size_t)(h * NPH + o)) * NENC];
    const float4* cl4 = (const float4*)ctxL;
    float s0 = 0.f, s1 = 0.f, s2 = 0.f, s3 = 0.f;
    for (int i = 0; i < NENC / 16; ++i) {
        s0 += f4dot(wrow[4 * i + 0], cl4[4 * i + 0]);
        s1 += f4dot(wrow[4 * i + 1], cl4[4 * i + 1]);
        s2 += f4dot(wrow[4 * i + 2], cl4[4 * i + 2]);
        s3 += f4dot(wrow[4 * i + 3], cl4[4 * i + 3]);
    }
    out[b * 1024 + h * NPH + o] = bout[h * NPH + o] + ((s0 + s1) + (s2 + s3));
}

extern "C" void kernel_launch(void* const* d_in, const int* in_sizes, int n_in,
                              void* d_out, int out_size, void* d_ws, size_t ws_size,
                              hipStream_t stream) {
    const float* enc   = (const float*)d_in[0];
    const int*   elen  = (const int*)d_in[1];
    const float* dec   = (const float*)d_in[2];
    const float* Wenc  = (const float*)d_in[3];
    const float* benc  = (const float*)d_in[4];
    const float* Wdec  = (const float*)d_in[5];
    const float* bdec  = (const float*)d_in[6];
    const float* wattn = (const float*)d_in[7];
    const float* Wconv = (const float*)d_in[8];
    const float* Wloc  = (const float*)d_in[9];
    const float* bloc  = (const float*)d_in[10];
    const float* Wout  = (const float*)d_in[11];
    const float* bout  = (const float*)d_in[12];
    float* out = (float*)d_out;

    char* ws = (char*)d_ws;
    size_t off = 0;
    auto alloc = [&](size_t bytes) { size_t o = off; off += (bytes + 255) & ~(size_t)255; return o; };
    unsigned short* encbf  = (unsigned short*)(ws + alloc((size_t)NB * NT * NENC * 2));
    unsigned short* wencbf = (unsigned short*)(ws + alloc((size_t)NH * NENC * 2));
    float* wcum  = (float*)(ws + alloc((size_t)256 * 102 * 4));
    float* wlocT = (float*)(ws + alloc((size_t)NC * NH * 4));
    float* dech  = (float*)(ws + alloc((size_t)NHEAD * NB * NATTN * 4));
    float* addp  = (float*)(ws + alloc((size_t)NB * NPROF * NH * 4));
    float* scor  = (float*)(ws + alloc((size_t)NHEAD * NB * TP * 4));
    float* attn  = (float*)(ws + alloc((size_t)NHEAD * NB * NT * 4));
    float* ctxp  = (float*)(ws + alloc((size_t)NTS * NHEAD * NB * NENC * 4));
    if (off > ws_size) return;  // insufficient workspace: bail (validation will flag it)

    hipFuncSetAttribute((const void*)k_gemm, hipFuncAttributeMaxDynamicSharedMemorySize, 16384);

    k_convert2<<<2048, 256, 0, stream>>>(enc, encbf, NB * NT * NENC / 8,
                                         Wenc, wencbf, NH * NENC / 8);
    k_prep<<<193, 256, 0, stream>>>(Wconv, wcum, Wloc, wlocT, dec, Wdec, bdec, dech);
    k_addprof<<<dim3((NPROF + 7) / 8, NB), 256, 0, stream>>>(wcum, dech, benc, bloc, wlocT, elen, addp);
    hipMemsetAsync(scor, 0, (size_t)NHEAD * NB * TP * 4, stream);
    hipMemsetAsync(out + NB * 1024, 0, (size_t)NB * NT * 4, stream);
    k_gemm<<<8192, 256, 16384, stream>>>(encbf, wencbf, addp, wattn, elen, scor);
    k_softmax<<<NHEAD * NB, 256, 0, stream>>>(scor, elen, attn, out);
    k_ctx<<<dim3(2, NTS, NB), 256, 0, stream>>>(encbf, attn, elen, ctxp);
    k_out<<<dim3(NB, NHEAD), 256, 0, stream>>>(ctxp, Wout, bout, out);
}

// Round 20
// 516.371 us; speedup vs baseline: 1.3790x; 1.3790x over previous
//
#include <hip/hip_runtime.h>
#include <hip/hip_bf16.h>
#include <cstdint>

#define NB 32
#define NT 2000
#define TP 2048
#define NENC 1024
#define NDEC 1024
#define NATTN 512
#define NHEAD 4
#define NH 2048      // NHEAD*NATTN
#define NC 64
#define NKS 50
#define NKLEN 101
#define NPH 256
#define NPROF 101
#define NTS 16       // k_ctx t-splits
#define TCH 125      // t per split

typedef __attribute__((ext_vector_type(8))) short bf16x8;
typedef __attribute__((ext_vector_type(4))) float f32x4;
typedef __attribute__((ext_vector_type(8))) unsigned short u16x8;

__device__ __forceinline__ void gload_lds16(const void* g, void* l) {
    __builtin_amdgcn_global_load_lds((__attribute__((address_space(1))) void*)(g),
                                     (__attribute__((address_space(3))) void*)(l), 16, 0, 0);
}

__device__ __forceinline__ unsigned short f2bf(float f) {
    unsigned u = __float_as_uint(f);
    return (unsigned short)((u + 0x7fffu + ((u >> 16) & 1u)) >> 16);
}

__device__ __forceinline__ float bf2f(unsigned short u) {
    return __uint_as_float((unsigned)u << 16);
}

__device__ __forceinline__ int prof_of(int t, int len) {
    if (t < NKS) return t;
    if (t < len - NKS) return NKS;
    if (t < len) return NKS + 1 + (t - (len - NKS));
    return NKS;
}

__device__ __forceinline__ float4 f4add3(float4 a, float4 b, float4 c) {
    return make_float4(a.x + b.x + c.x, a.y + b.y + c.y, a.z + b.z + c.z, a.w + b.w + c.w);
}
__device__ __forceinline__ float4 f4fma(float s, float4 a, float4 acc) {
    return make_float4(fmaf(s, a.x, acc.x), fmaf(s, a.y, acc.y),
                       fmaf(s, a.z, acc.z), fmaf(s, a.w, acc.w));
}
__device__ __forceinline__ float f4dot(float4 a, float4 b) {
    return fmaf(a.x, b.x, fmaf(a.y, b.y, fmaf(a.z, b.z, a.w * b.w)));
}

// ------------- fused f32 -> bf16 conversion for enc AND Wenc (one launch) -----
__global__ void k_convert2(const float* __restrict__ srcA, unsigned short* __restrict__ dstA, int n8A,
                           const float* __restrict__ srcB, unsigned short* __restrict__ dstB, int n8B) {
    int stride = gridDim.x * blockDim.x;
    int total = n8A + n8B;
    for (int i = blockIdx.x * blockDim.x + threadIdx.x; i < total; i += stride) {
        const float* src; unsigned short* dst; int j;
        if (i < n8A) { src = srcA; dst = dstA; j = i; }
        else         { src = srcB; dst = dstB; j = i - n8A; }
        const float4* s = (const float4*)(src) + (size_t)j * 2;
        float4 x = s[0], y = s[1];
        u16x8 o;
        o[0] = f2bf(x.x); o[1] = f2bf(x.y); o[2] = f2bf(x.z); o[3] = f2bf(x.w);
        o[4] = f2bf(y.x); o[5] = f2bf(y.y); o[6] = f2bf(y.z); o[7] = f2bf(y.w);
        *((u16x8*)dst + j) = o;
    }
}

// ------- fused prep: wcum (block 0) | wlocT (blocks 1..64) | dech (65..192) ---
__global__ void k_prep(const float* __restrict__ Wconv, float* __restrict__ wcum,
                       const float* __restrict__ Wloc, float* __restrict__ wlocT,
                       const float* __restrict__ dec, const float* __restrict__ Wdec,
                       const float* __restrict__ bdec, float* __restrict__ dech) {
    int blk = blockIdx.x;
    int tid = threadIdx.x;
    if (blk == 0) {
        float c = 0.f;
        wcum[tid * 102] = 0.f;
        for (int k = 0; k < NKLEN; ++k) {
            c += Wconv[tid * NKLEN + k];
            wcum[tid * 102 + k + 1] = c;
        }
    } else if (blk <= 64) {
        int c = blk - 1;
        for (int n = tid; n < NH; n += 256)
            wlocT[c * NH + n] = Wloc[(size_t)n * NC + c];
    } else {
        int idx = blk - 65;
        int h = idx >> 5, b = idx & 31;
        __shared__ float dl[NDEC];
        for (int r = 0; r < 4; ++r) dl[tid + r * 256] = dec[b * NDEC + tid + r * 256];
        __syncthreads();
        for (int a2 = 0; a2 < 2; ++a2) {
            int a = tid + a2 * 256;
            const float4* wr = (const float4*)&Wdec[((size_t)(h * NATTN + a)) * NDEC];
            float acc = 0.f;
            for (int e4 = 0; e4 < NDEC / 4; ++e4) {
                float4 w4 = wr[e4];
                acc += w4.x * dl[e4 * 4] + w4.y * dl[e4 * 4 + 1] + w4.z * dl[e4 * 4 + 2] + w4.w * dl[e4 * 4 + 3];
            }
            dech[(h * NB + b) * NATTN + a] = acc + bdec[h * NATTN + a];
        }
    }
}

// ---- add[b][p][n] = dec_h + benc + bloc + WlocT^T . conv_profile(p), PP=8 ----
__global__ void k_addprof(const float* __restrict__ wcum, const float* __restrict__ dech,
                          const float* __restrict__ benc, const float* __restrict__ bloc,
                          const float* __restrict__ wlocT, const int* __restrict__ enc_len,
                          float* __restrict__ addp) {
    int p0 = blockIdx.x * 8, b = blockIdx.y;
    int len = enc_len[b];
    __shared__ float convp[8][256];
    int tid = threadIdx.x;
    float invl = 1.f / (float)len;
#pragma unroll
    for (int pp = 0; pp < 8; ++pp) {
        int p = min(p0 + pp, NPROF - 1);
        int kmin, kmax;
        if (p < NKS)       { kmin = NKS - p; kmax = min(NKLEN, len - p + NKS); }
        else if (p == NKS) { kmin = 0;       kmax = NKLEN; }
        else               { kmin = 0;       kmax = 151 - p; }
        if (kmax < kmin) kmax = kmin;
        convp[pp][tid] = (wcum[tid * 102 + kmax] - wcum[tid * 102 + kmin]) * invl;
    }
    __syncthreads();
    int h0 = tid >> 7, h1 = 2 + h0;
    int n40 = tid, n41 = 256 + tid;   // float4 indices into the 2048-wide n dim
    const float4* dech4 = (const float4*)dech;
    const float4* benc4 = (const float4*)benc;
    const float4* bloc4 = (const float4*)bloc;
    float4 base0 = f4add3(dech4[(h0 * NB + b) * 128 + (tid & 127)], benc4[n40], bloc4[n40]);
    float4 base1 = f4add3(dech4[(h1 * NB + b) * 128 + (tid & 127)], benc4[n41], bloc4[n41]);
    float4 acc[8][2];
#pragma unroll
    for (int pp = 0; pp < 8; ++pp) { acc[pp][0] = base0; acc[pp][1] = base1; }
    const float4* wT4 = (const float4*)wlocT;
#pragma unroll 2
    for (int c = 0; c < NC; ++c) {
        float4 w0 = wT4[c * 512 + n40];
        float4 w1 = wT4[c * 512 + n41];
#pragma unroll
        for (int pp = 0; pp < 8; ++pp) {
            acc[pp][0] = f4fma(convp[pp][h0 * 64 + c], w0, acc[pp][0]);
            acc[pp][1] = f4fma(convp[pp][h1 * 64 + c], w1, acc[pp][1]);
        }
    }
    float4* addp4 = (float4*)addp;
#pragma unroll
    for (int pp = 0; pp < 8; ++pp) {
        int p = p0 + pp;
        if (p < NPROF) {
            addp4[((size_t)(b * NPROF + p)) * 512 + n40] = acc[pp][0];
            addp4[((size_t)(b * NPROF + p)) * 512 + n41] = acc[pp][1];
        }
    }
}

// ---------------- main fused GEMM + tanh + wattn-reduce -> scores -------------
// v5 (PROVEN OPTIMUM, ~320us @ 41% occ): 128x128 block tile, 4 waves, 64x64
// wave tile (acc[4][4], 128 regs/wave), 2-deep 16KB ring (32 KB LDS, 3
// blocks/CU), chunk-XOR swizzle, one __syncthreads per kt.
// Probed & rejected: 256^2/8-wave (R3-R6), persistent (R7), 48KB 3-ring
// (R14: occ 40->30), 192x128 (R17: occ 41->30), B-in-regs (R19: uncoalesced
// B loads, 16 transactions/instr -> 538us). Occupancy is the carrying lever;
// global_load_lds staging IS the coalescing device.
__global__ __launch_bounds__(256, 3) void k_gemm(
        const unsigned short* __restrict__ encbf, const unsigned short* __restrict__ wencbf,
        const float* __restrict__ addp, const float* __restrict__ wattn,
        const int* __restrict__ enc_len, float* __restrict__ scores) {
    extern __shared__ char smem[];
    int bid = blockIdx.x;
    int L = (bid & 7) * 1024 + (bid >> 3);   // bijective XCD swizzle (8192%8==0)
    int nt = L & 15, ty = (L >> 4) & 15, b = L >> 8;
    int n0 = nt * 128, t0 = ty * 128;
    int len = enc_len[b];
    if (t0 >= len) return;  // fully-masked tile
    int tid = threadIdx.x, lane = tid & 63, w = tid >> 6;  // w in 0..3
    int wr = w >> 1, wc = w & 1;
    int ro = lane & 15, g4 = lane >> 4;

    int lrow = lane >> 2;
    int csrc = ((lane & 3) ^ ((lane >> 3) & 3)) * 8;   // elements
    const unsigned short* aB = encbf + (size_t)b * NT * NENC;
    int rA[2], rB[2];
#pragma unroll
    for (int g = 0; g < 2; ++g) { int t = t0 + g * 64 + w * 16 + lrow; rA[g] = t < NT ? t : NT - 1; }
#pragma unroll
    for (int g = 0; g < 2; ++g) rB[g] = n0 + g * 64 + w * 16 + lrow;

    auto STAGE = [&](int q, int kt) {
        char* base = smem + q * 16384;
        int k0 = kt * 32 + csrc;
#pragma unroll
        for (int g = 0; g < 2; ++g)
            gload_lds16(aB + (size_t)rA[g] * NENC + k0, base + g * 4096 + w * 1024);
#pragma unroll
        for (int g = 0; g < 2; ++g)
            gload_lds16(wencbf + (size_t)rB[g] * NENC + k0, base + 8192 + g * 4096 + w * 1024);
    };

    f32x4 acc[4][4] = {};
    int swb = (g4 ^ ((ro >> 1) & 3)) * 16;               // swizzled chunk byte on read
    int rdA = (wr * 64 + ro) * 64 + swb;                  // + m*1024
    int rdB = 8192 + (wc * 64 + ro) * 64 + swb;           // + n*1024

    STAGE(0, 0);
    __syncthreads();
#pragma unroll 2
    for (int kt = 0; kt < 32; ++kt) {
        int q = kt & 1;
        if (kt < 31) STAGE(q ^ 1, kt + 1);
        const char* base = smem + q * 16384;
        bf16x8 A[4], Bf[4];
#pragma unroll
        for (int m = 0; m < 4; ++m) A[m] = *(const bf16x8*)(base + rdA + m * 1024);
#pragma unroll
        for (int n = 0; n < 4; ++n) Bf[n] = *(const bf16x8*)(base + rdB + n * 1024);
        __builtin_amdgcn_s_setprio(1);
#pragma unroll
        for (int m = 0; m < 4; ++m) {
            acc[m][0] = __builtin_amdgcn_mfma_f32_16x16x32_bf16(A[m], Bf[0], acc[m][0], 0, 0, 0);
            acc[m][1] = __builtin_amdgcn_mfma_f32_16x16x32_bf16(A[m], Bf[1], acc[m][1], 0, 0, 0);
            acc[m][2] = __builtin_amdgcn_mfma_f32_16x16x32_bf16(A[m], Bf[2], acc[m][2], 0, 0, 0);
            acc[m][3] = __builtin_amdgcn_mfma_f32_16x16x32_bf16(A[m], Bf[3], acc[m][3], 0, 0, 0);
        }
        __builtin_amdgcn_s_setprio(0);
        __syncthreads();
    }

    // epilogue: tanh(acc+add)*wattn, 16-lane reduce over n, atomicAdd to scores
    int h = n0 >> 9;
    float wat[4];
#pragma unroll
    for (int n = 0; n < 4; ++n) wat[n] = wattn[n0 + wc * 64 + n * 16 + ro];
    const float* addb = addp + (size_t)b * NPROF * NH + n0 + wc * 64 + ro;
    float* sr = scores + ((size_t)(h * NB + b)) * TP;
#pragma unroll
    for (int m = 0; m < 4; ++m) {
#pragma unroll
        for (int e = 0; e < 4; ++e) {
            int t = t0 + wr * 64 + m * 16 + g4 * 4 + e;
            int tc = t < NT ? t : NT - 1;
            const float* arow = addb + (size_t)prof_of(tc, len) * NH;
            float s = 0.f;
#pragma unroll
            for (int n = 0; n < 4; ++n) {
                float v = acc[m][n][e] + arow[n * 16];
                v = fminf(fmaxf(v, -15.f), 15.f);
                float e2 = __expf(2.f * v);
                s += ((e2 - 1.f) / (e2 + 1.f)) * wat[n];
            }
            s += __shfl_xor(s, 1); s += __shfl_xor(s, 2);
            s += __shfl_xor(s, 4); s += __shfl_xor(s, 8);
            if (ro == 0 && t < NT) atomicAdd(&sr[t], s);
        }
    }
}

// ------- masked softmax over t per (h,b) -> attn, + fused mean into out -------
__global__ void k_softmax(const float* __restrict__ scores, const int* __restrict__ enc_len,
                          float* __restrict__ attn, float* __restrict__ out) {
    int h = blockIdx.x >> 5, b = blockIdx.x & 31;
    int len = enc_len[b];
    int tid = threadIdx.x;
    const float* row = scores + ((size_t)(h * NB + b)) * TP;
    __shared__ float red[4];
    float m = -1e30f;
    for (int t = tid; t < len; t += 256) m = fmaxf(m, row[t]);
    for (int d = 32; d; d >>= 1) m = fmaxf(m, __shfl_xor(m, d));
    if ((tid & 63) == 0) red[tid >> 6] = m;
    __syncthreads();
    m = fmaxf(fmaxf(red[0], red[1]), fmaxf(red[2], red[3]));
    __syncthreads();
    float z = 0.f;
    for (int t = tid; t < len; t += 256) z += __expf(row[t] - m);
    for (int d = 32; d; d >>= 1) z += __shfl_xor(z, d);
    if ((tid & 63) == 0) red[tid >> 6] = z;
    __syncthreads();
    z = red[0] + red[1] + red[2] + red[3];
    float inv = 1.f / z;
    float* ow = out + NB * 1024 + b * NT;
    for (int t = tid; t < NT; t += 256) {
        float av = (t < len) ? __expf(row[t] - m) * inv : 0.f;
        attn[((size_t)(h * NB + b)) * NT + t] = av;
        atomicAdd(&ow[t], 0.25f * av);   // fused attn_weight mean over heads
    }
}

// ---- ctx partials: [ts][h][b][e], NTS=16 t-splits (4 blk/CU), unroll-2 -------
__global__ void k_ctx(const unsigned short* __restrict__ encbf, const float* __restrict__ attn,
                      const int* __restrict__ enc_len, float* __restrict__ ctxp) {
    int ec = blockIdx.x, ts = blockIdx.y, b = blockIdx.z;
    int tid = threadIdx.x;
    __shared__ float attnL[NHEAD][TCH];
    int t0 = ts * TCH;
    for (int i = tid; i < NHEAD * TCH; i += 256) {
        int hh = i / TCH, tt = i - hh * TCH;
        attnL[hh][tt] = attn[((size_t)(hh * NB + b)) * NT + t0 + tt];
    }
    __syncthreads();
    int len = enc_len[b];
    int t1 = min(t0 + TCH, len);
    int e0 = ec * 512 + tid * 2;
    const unsigned* erow = (const unsigned*)(encbf + (size_t)b * NT * NENC);
    float a0x = 0.f, a0y = 0.f, a1x = 0.f, a1y = 0.f;
    float a2x = 0.f, a2y = 0.f, a3x = 0.f, a3y = 0.f;
    int t = t0;
    for (; t + 2 <= t1; t += 2) {
        unsigned pv0 = erow[((size_t)t * NENC + e0) >> 1];
        unsigned pv1 = erow[((size_t)(t + 1) * NENC + e0) >> 1];
        int tt = t - t0;
        float ex0 = bf2f((unsigned short)(pv0 & 0xffff));
        float ey0 = bf2f((unsigned short)(pv0 >> 16));
        float w00 = attnL[0][tt], w10 = attnL[1][tt], w20 = attnL[2][tt], w30 = attnL[3][tt];
        a0x = fmaf(w00, ex0, a0x); a0y = fmaf(w00, ey0, a0y);
        a1x = fmaf(w10, ex0, a1x); a1y = fmaf(w10, ey0, a1y);
        a2x = fmaf(w20, ex0, a2x); a2y = fmaf(w20, ey0, a2y);
        a3x = fmaf(w30, ex0, a3x); a3y = fmaf(w30, ey0, a3y);
        float ex1 = bf2f((unsigned short)(pv1 & 0xffff));
        float ey1 = bf2f((unsigned short)(pv1 >> 16));
        float w01 = attnL[0][tt + 1], w11 = attnL[1][tt + 1], w21 = attnL[2][tt + 1], w31 = attnL[3][tt + 1];
        a0x = fmaf(w01, ex1, a0x); a0y = fmaf(w01, ey1, a0y);
        a1x = fmaf(w11, ex1, a1x); a1y = fmaf(w11, ey1, a1y);
        a2x = fmaf(w21, ex1, a2x); a2y = fmaf(w21, ey1, a2y);
        a3x = fmaf(w31, ex1, a3x); a3y = fmaf(w31, ey1, a3y);
    }
    for (; t < t1; ++t) {
        unsigned pv = erow[((size_t)t * NENC + e0) >> 1];
        float ex = bf2f((unsigned short)(pv & 0xffff));
        float ey = bf2f((unsigned short)(pv >> 16));
        int tt = t - t0;
        float w0 = attnL[0][tt], w1 = attnL[1][tt], w2 = attnL[2][tt], w3 = attnL[3][tt];
        a0x = fmaf(w0, ex, a0x); a0y = fmaf(w0, ey, a0y);
        a1x = fmaf(w1, ex, a1x); a1y = fmaf(w1, ey, a1y);
        a2x = fmaf(w2, ex, a2x); a2y = fmaf(w2, ey, a2y);
        a3x = fmaf(w3, ex, a3x); a3y = fmaf(w3, ey, a3y);
    }
    float2* c0 = (float2*)&ctxp[(((size_t)ts * NHEAD + 0) * NB + b) * NENC + e0];
    float2* c1 = (float2*)&ctxp[(((size_t)ts * NHEAD + 1) * NB + b) * NENC + e0];
    float2* c2 = (float2*)&ctxp[(((size_t)ts * NHEAD + 2) * NB + b) * NENC + e0];
    float2* c3 = (float2*)&ctxp[(((size_t)ts * NHEAD + 3) * NB + b) * NENC + e0];
    *c0 = make_float2(a0x, a0y);
    *c1 = make_float2(a1x, a1y);
    *c2 = make_float2(a2x, a2y);
    *c3 = make_float2(a3x, a3y);
}

// ------ out[h][b][o] = Wout[h,o,:].ctx + bout  (4-way ILP e-chains) -----------
__global__ void k_out(const float* __restrict__ ctxp, const float* __restrict__ Wout,
                      const float* __restrict__ bout, float* __restrict__ out) {
    int b = blockIdx.x, h = blockIdx.y;
    int tid = threadIdx.x;
    __shared__ __align__(16) float ctxL[NENC];
    for (int r = 0; r < 4; ++r) {
        int e = tid + r * 256;
        float s = 0.f;
#pragma unroll
        for (int s4 = 0; s4 < NTS; ++s4) s += ctxp[(((size_t)s4 * NHEAD + h) * NB + b) * NENC + e];
        ctxL[e] = s;
    }
    __syncthreads();
    int o = tid;
    const float4* wrow = (const float4*)&Wout[((size_t)(h * NPH + o)) * NENC];
    const float4* cl4 = (const float4*)ctxL;
    float s0 = 0.f, s1 = 0.f, s2 = 0.f, s3 = 0.f;
    for (int i = 0; i < NENC / 16; ++i) {
        s0 += f4dot(wrow[4 * i + 0], cl4[4 * i + 0]);
        s1 += f4dot(wrow[4 * i + 1], cl4[4 * i + 1]);
        s2 += f4dot(wrow[4 * i + 2], cl4[4 * i + 2]);
        s3 += f4dot(wrow[4 * i + 3], cl4[4 * i + 3]);
    }
    out[b * 1024 + h * NPH + o] = bout[h * NPH + o] + ((s0 + s1) + (s2 + s3));
}

extern "C" void kernel_launch(void* const* d_in, const int* in_sizes, int n_in,
                              void* d_out, int out_size, void* d_ws, size_t ws_size,
                              hipStream_t stream) {
    const float* enc   = (const float*)d_in[0];
    const int*   elen  = (const int*)d_in[1];
    const float* dec   = (const float*)d_in[2];
    const float* Wenc  = (const float*)d_in[3];
    const float* benc  = (const float*)d_in[4];
    const float* Wdec  = (const float*)d_in[5];
    const float* bdec  = (const float*)d_in[6];
    const float* wattn = (const float*)d_in[7];
    const float* Wconv = (const float*)d_in[8];
    const float* Wloc  = (const float*)d_in[9];
    const float* bloc  = (const float*)d_in[10];
    const float* Wout  = (const float*)d_in[11];
    const float* bout  = (const float*)d_in[12];
    float* out = (float*)d_out;

    char* ws = (char*)d_ws;
    size_t off = 0;
    auto alloc = [&](size_t bytes) { size_t o = off; off += (bytes + 255) & ~(size_t)255; return o; };
    unsigned short* encbf  = (unsigned short*)(ws + alloc((size_t)NB * NT * NENC * 2));
    unsigned short* wencbf = (unsigned short*)(ws + alloc((size_t)NH * NENC * 2));
    float* wcum  = (float*)(ws + alloc((size_t)256 * 102 * 4));
    float* wlocT = (float*)(ws + alloc((size_t)NC * NH * 4));
    float* dech  = (float*)(ws + alloc((size_t)NHEAD * NB * NATTN * 4));
    float* addp  = (float*)(ws + alloc((size_t)NB * NPROF * NH * 4));
    float* scor  = (float*)(ws + alloc((size_t)NHEAD * NB * TP * 4));
    float* attn  = (float*)(ws + alloc((size_t)NHEAD * NB * NT * 4));
    float* ctxp  = (float*)(ws + alloc((size_t)NTS * NHEAD * NB * NENC * 4));
    if (off > ws_size) return;  // insufficient workspace: bail (validation will flag it)

    hipFuncSetAttribute((const void*)k_gemm, hipFuncAttributeMaxDynamicSharedMemorySize, 32768);

    k_convert2<<<2048, 256, 0, stream>>>(enc, encbf, NB * NT * NENC / 8,
                                         Wenc, wencbf, NH * NENC / 8);
    k_prep<<<193, 256, 0, stream>>>(Wconv, wcum, Wloc, wlocT, dec, Wdec, bdec, dech);
    k_addprof<<<dim3((NPROF + 7) / 8, NB), 256, 0, stream>>>(wcum, dech, benc, bloc, wlocT, elen, addp);
    hipMemsetAsync(scor, 0, (size_t)NHEAD * NB * TP * 4, stream);
    hipMemsetAsync(out + NB * 1024, 0, (size_t)NB * NT * 4, stream);
    k_gemm<<<8192, 256, 32768, stream>>>(encbf, wencbf, addp, wattn, elen, scor);
    k_softmax<<<NHEAD * NB, 256, 0, stream>>>(scor, elen, attn, out);
    k_ctx<<<dim3(2, NTS, NB), 256, 0, stream>>>(encbf, attn, elen, ctxp);
    k_out<<<dim3(NB, NHEAD), 256, 0, stream>>>(ctxp, Wout, bout, out);
}